// Round 1
// baseline (295.759 us; speedup 1.0000x reference)
//
#include <hip/hip_runtime.h>
#include <math.h>

// Problem constants (B,S,D,C) = (64, 576, 768, 200)
#define Bsz  64
#define Ssz  576
#define Dsz  768
#define Csz  200
#define NPAD 208        // C padded to 13 tiles of 16
#define MT   64         // M-tile rows per block; 576 % 64 == 0 -> no cross-batch tiles
#define BK   64         // K-tile
#define LDP  (BK + 8)   // LDS leading-dim pad (+8 bf16 = 16B keeps b128 alignment, 2-way banks)

typedef short short8 __attribute__((ext_vector_type(8)));
typedef float f32x4  __attribute__((ext_vector_type(4)));

__device__ inline unsigned short f2bf(float f) {
    union { float f; unsigned int u; } v; v.f = f;
    // round-to-nearest-even fp32 -> bf16 (inputs are finite random normals; no NaN path needed)
    return (unsigned short)((v.u + 0x7FFFu + ((v.u >> 16) & 1u)) >> 16);
}

// Fused: logits = X * W^T (bf16 MFMA), att = sigmoid(logits + b),
// partial[b,c] += sum_rows att * rowsum(row).  X rows are (b*S+s).
__global__ __launch_bounds__(256) void attn_kernel(
    const float* __restrict__ X,      // (B*S, D) fp32
    const float* __restrict__ W,      // (C, D)   fp32
    const float* __restrict__ attn_b, // (C,)
    float* __restrict__ accum)        // (B, C) fp32, pre-zeroed (lives in d_out)
{
    __shared__ unsigned short sX[MT][LDP];
    __shared__ unsigned short sW[NPAD][LDP];
    __shared__ float rowsumL[MT];
    __shared__ float colsumL[NPAD];

    const int tid  = threadIdx.x;
    const int lane = tid & 63;
    const int wv   = tid >> 6;               // wave 0..3, handles rows [wv*16, wv*16+16)
    const int rowbase = blockIdx.x * MT;
    const int bidx    = rowbase / Ssz;       // whole tile is inside one batch (576 % 64 == 0)

    if (tid < MT)   rowsumL[tid] = 0.f;
    if (tid < NPAD) colsumL[tid] = 0.f;

    f32x4 acc[13];
#pragma unroll
    for (int t = 0; t < 13; ++t) acc[t] = (f32x4){0.f, 0.f, 0.f, 0.f};

    float rs[4] = {0.f, 0.f, 0.f, 0.f};      // exact fp32 rowsum partials
    const int r0 = tid >> 4;                 // 0..15
    const int c4 = tid & 15;                 // float4 column within tile

    for (int kt = 0; kt < Dsz / BK; ++kt) {
        const int kk = kt * BK;
        // ---- stage X tile (64 x 64), fp32 load -> rowsum accumulate -> bf16 LDS
#pragma unroll
        for (int i = 0; i < 4; ++i) {
            const int row = r0 + 16 * i;
            const float4 v = *(const float4*)(X + (size_t)(rowbase + row) * Dsz + kk + c4 * 4);
            rs[i] += v.x + v.y + v.z + v.w;
            ushort4 h;
            h.x = f2bf(v.x); h.y = f2bf(v.y); h.z = f2bf(v.z); h.w = f2bf(v.w);
            *(ushort4*)&sX[row][c4 * 4] = h;
        }
        // ---- stage W tile (208 x 64), rows >= 200 zero-padded
#pragma unroll
        for (int i = 0; i < 13; ++i) {
            const int row = r0 + 16 * i;
            float4 v = {0.f, 0.f, 0.f, 0.f};
            if (row < Csz)
                v = *(const float4*)(W + (size_t)row * Dsz + kk + c4 * 4);
            ushort4 h;
            h.x = f2bf(v.x); h.y = f2bf(v.y); h.z = f2bf(v.z); h.w = f2bf(v.w);
            *(ushort4*)&sW[row][c4 * 4] = h;
        }
        __syncthreads();
        // ---- MFMA: wave wv computes rows [wv*16,+16) x all 13 col-tiles
#pragma unroll
        for (int k2 = 0; k2 < BK; k2 += 32) {
            const short8 a = *(const short8*)&sX[wv * 16 + (lane & 15)][k2 + (lane >> 4) * 8];
#pragma unroll
            for (int t = 0; t < 13; ++t) {
                const short8 bf = *(const short8*)&sW[t * 16 + (lane & 15)][k2 + (lane >> 4) * 8];
                acc[t] = __builtin_amdgcn_mfma_f32_16x16x32_bf16(a, bf, acc[t], 0, 0, 0);
            }
        }
        __syncthreads();
    }

    // finalize rowsums (each (row, c4) column-block owned by exactly one thread)
#pragma unroll
    for (int i = 0; i < 4; ++i) atomicAdd(&rowsumL[r0 + 16 * i], rs[i]);
    __syncthreads();

    // epilogue: att = sigmoid(logit + bias); colsum[c] += att * rowsum[row]
    // C/D layout: col = lane&15 (n), row = (lane>>4)*4 + reg (m)
#pragma unroll
    for (int t = 0; t < 13; ++t) {
        const int c = t * 16 + (lane & 15);
        if (c < Csz) {
            const float bias = attn_b[c];
            float s = 0.f;
#pragma unroll
            for (int r = 0; r < 4; ++r) {
                const int row = wv * 16 + ((lane >> 4) << 2) + r;
                const float x = acc[t][r] + bias;
                const float att = 1.f / (1.f + __expf(-x));
                s += att * rowsumL[row];
            }
            atomicAdd(&colsumL[c], s);
        }
    }
    __syncthreads();
    if (tid < Csz) atomicAdd(&accum[bidx * Csz + tid], colsumL[tid]);
}

// Tiny fp32 classifier + final combine:
// out[b,c] = class_token[b]·gc_w[c] + gc_b[c] + lam * accum[b,c] / (S*D)
__global__ __launch_bounds__(256) void gc_kernel(
    const float* __restrict__ ct,   // (B, D)
    const float* __restrict__ gw,   // (C, D)
    const float* __restrict__ gb,   // (C,)
    const float* __restrict__ lam,  // (1,)
    float* __restrict__ out)        // (B, C): holds attention accum on entry
{
    __shared__ float s_ct[Dsz];
    const int b   = blockIdx.x;
    const int tid = threadIdx.x;
    for (int d = tid; d < Dsz; d += 256) s_ct[d] = ct[b * Dsz + d];
    __syncthreads();
    if (tid < Csz) {
        const float* wr = gw + (size_t)tid * Dsz;
        float accv = gb[tid];
#pragma unroll 4
        for (int d = 0; d < Dsz; d += 4) {
            const float4 wv = *(const float4*)(wr + d);
            accv += wv.x * s_ct[d] + wv.y * s_ct[d + 1] + wv.z * s_ct[d + 2] + wv.w * s_ct[d + 3];
        }
        const float a = out[b * Csz + tid];
        out[b * Csz + tid] = accv + lam[0] * a * (1.f / ((float)Ssz * (float)Dsz));
    }
}

extern "C" void kernel_launch(void* const* d_in, const int* in_sizes, int n_in,
                              void* d_out, int out_size, void* d_ws, size_t ws_size,
                              hipStream_t stream) {
    const float* X   = (const float*)d_in[0];  // patch_tokens (B,S,D)
    const float* ct  = (const float*)d_in[1];  // class_token  (B,D)
    const float* aw  = (const float*)d_in[2];  // attn_w       (C,D)
    const float* ab  = (const float*)d_in[3];  // attn_b       (C,)
    const float* gw  = (const float*)d_in[4];  // gc_w         (C,D)
    const float* gb  = (const float*)d_in[5];  // gc_b         (C,)
    const float* lam = (const float*)d_in[6];  // lam          (1,)
    float* out = (float*)d_out;                // (B,C) fp32

    // out doubles as the attention-score accumulator; zero it (poisoned 0xAA).
    hipMemsetAsync(out, 0, Bsz * Csz * sizeof(float), stream);
    attn_kernel<<<(Bsz * Ssz) / MT, 256, 0, stream>>>(X, aw, ab, out);
    gc_kernel<<<Bsz, 256, 0, stream>>>(ct, gw, gb, lam, out);
}

// Round 2
// 261.622 us; speedup vs baseline: 1.1305x; 1.1305x over previous
//
#include <hip/hip_runtime.h>
#include <math.h>

// (B,S,D,C) = (64, 576, 768, 200)
#define Bsz  64
#define Ssz  576
#define Dsz  768
#define Csz  200
#define NPAD 208        // C padded to 13 tiles of 16
#define MT   64         // rows per block (576 % 64 == 0: tile never crosses batch)
#define BK   64         // K-tile
#define LDP  (BK + 8)   // LDS leading dim in shorts: 144B stride -> conflict-free b128

typedef short short8 __attribute__((ext_vector_type(8)));
typedef float f32x4  __attribute__((ext_vector_type(4)));

__device__ inline unsigned short f2bf_rne(float f) {
    union { float f; unsigned int u; } v; v.f = f;
    return (unsigned short)((v.u + 0x7FFFu + ((v.u >> 16) & 1u)) >> 16);
}

// two fp32 -> packed bf16x2, round-half-up (1 add each + 1 v_perm)
__device__ inline unsigned int pack2bf(float lo, float hi) {
    union { float f; unsigned int u; } a, b; a.f = lo; b.f = hi;
    return __builtin_amdgcn_perm(b.u + 0x8000u, a.u + 0x8000u, 0x07060302u);
}

// one-time: W (200x768 fp32) -> padded bf16 (208x768), rows >=200 zeroed
__global__ __launch_bounds__(256) void prep_w(const float* __restrict__ W,
                                              unsigned short* __restrict__ Wb) {
    const int i   = blockIdx.x * 256 + threadIdx.x;  // float4-group index, grid covers NPAD*768/4
    const int row = i / (Dsz / 4);
    const int col = (i % (Dsz / 4)) * 4;
    float4 v = {0.f, 0.f, 0.f, 0.f};
    if (row < Csz) v = *(const float4*)(W + (size_t)row * Dsz + col);
    ushort4 h;
    h.x = f2bf_rne(v.x); h.y = f2bf_rne(v.y); h.z = f2bf_rne(v.z); h.w = f2bf_rne(v.w);
    *(ushort4*)(Wb + (size_t)row * Dsz + col) = h;
}

// Fused: logits = X * W^T (bf16 MFMA) -> sigmoid -> rowsum-weighted S-reduction
__global__ __launch_bounds__(256) void attn_kernel(
    const float* __restrict__ X,            // (B*S, D) fp32
    const unsigned short* __restrict__ Wb,  // (NPAD, D) bf16 (pre-converted)
    const float* __restrict__ attn_b,       // (C,)
    float* __restrict__ accum)              // (B, C) fp32 accumulator (= d_out)
{
    __shared__ unsigned short sX[MT][LDP];
    __shared__ unsigned short sW[NPAD][LDP];
    __shared__ float rowsumL[MT];
    __shared__ float colsumL[NPAD];

    const int tid  = threadIdx.x;
    const int lane = tid & 63;
    const int wv   = tid >> 6;
    const int rowbase = blockIdx.x * MT;
    const int bidx    = rowbase / Ssz;

    if (tid < MT)   rowsumL[tid] = 0.f;
    if (tid < NPAD) colsumL[tid] = 0.f;

    f32x4 acc[13];
#pragma unroll
    for (int t = 0; t < 13; ++t) acc[t] = (f32x4){0.f, 0.f, 0.f, 0.f};

    // X staging: thread owns rows {xrow, xrow+32}, 8 consecutive cols (one b128 line)
    const int xrow = tid >> 3;       // 0..31
    const int xc8  = tid & 7;        // 8-elt column chunk
    float rs[2] = {0.f, 0.f};

    for (int kt = 0; kt < Dsz / BK; ++kt) {
        const int kk = kt * BK;
        // ---- stage X: fp32 load -> rowsum -> packed bf16, full b128 LDS lines
#pragma unroll
        for (int i = 0; i < 2; ++i) {
            const int row = xrow + 32 * i;
            const float* p = X + (size_t)(rowbase + row) * Dsz + kk + xc8 * 8;
            const float4 v0 = *(const float4*)(p);
            const float4 v1 = *(const float4*)(p + 4);
            rs[i] += (v0.x + v0.y + v0.z + v0.w) + (v1.x + v1.y + v1.z + v1.w);
            uint4 u;
            u.x = pack2bf(v0.x, v0.y); u.y = pack2bf(v0.z, v0.w);
            u.z = pack2bf(v1.x, v1.y); u.w = pack2bf(v1.z, v1.w);
            *(uint4*)&sX[row][xc8 * 8] = u;
        }
        // ---- stage W: already bf16 — pure 16B copy, 6.5 passes of 256 threads
#pragma unroll
        for (int p = 0; p < 7; ++p) {
            const int idx = p * 256 + tid;          // 16B-chunk index, 1664 total
            if (idx < (NPAD * BK * 2) / 16) {
                const int wrow = idx >> 3;          // 8 chunks per 64-col row
                const int wq   = idx & 7;
                const uint4 v = *(const uint4*)(Wb + (size_t)wrow * Dsz + kk + wq * 8);
                *(uint4*)&sW[wrow][wq * 8] = v;
            }
        }
        __syncthreads();
        // ---- MFMA: wave wv owns row-tile wv, all 13 col-tiles
#pragma unroll
        for (int k2 = 0; k2 < BK; k2 += 32) {
            const short8 a = *(const short8*)&sX[wv * 16 + (lane & 15)][k2 + (lane >> 4) * 8];
#pragma unroll
            for (int t = 0; t < 13; ++t) {
                const short8 bf = *(const short8*)&sW[t * 16 + (lane & 15)][k2 + (lane >> 4) * 8];
                acc[t] = __builtin_amdgcn_mfma_f32_16x16x32_bf16(a, bf, acc[t], 0, 0, 0);
            }
        }
        __syncthreads();
    }

    // exact fp32 rowsums (each thread owns 8 cols of 2 rows)
#pragma unroll
    for (int i = 0; i < 2; ++i) atomicAdd(&rowsumL[xrow + 32 * i], rs[i]);
    __syncthreads();

    // epilogue: att = sigmoid(logit + bias); colsum[c] += att * rowsum[row]
    // C/D layout: col = lane&15, row = (lane>>4)*4 + reg
#pragma unroll
    for (int t = 0; t < 13; ++t) {
        const int c = t * 16 + (lane & 15);
        if (c < Csz) {
            const float bias = attn_b[c];
            float s = 0.f;
#pragma unroll
            for (int r = 0; r < 4; ++r) {
                const int row = wv * 16 + ((lane >> 4) << 2) + r;
                const float x = acc[t][r] + bias;
                s += rowsumL[row] / (1.f + __expf(-x));
            }
            atomicAdd(&colsumL[c], s);
        }
    }
    __syncthreads();
    if (tid < Csz) atomicAdd(&accum[bidx * Csz + tid], colsumL[tid]);
}

// global classifier + combine: wave-per-class, grid (B, 50)
__global__ __launch_bounds__(256) void gc_kernel(
    const float* __restrict__ ct,   // (B, D)
    const float* __restrict__ gw,   // (C, D)
    const float* __restrict__ gb,   // (C,)
    const float* __restrict__ lam,  // (1,)
    float* __restrict__ out)        // (B, C): attention accum on entry
{
    const int b    = blockIdx.x;
    const int wv   = threadIdx.x >> 6;
    const int lane = threadIdx.x & 63;
    const int c    = blockIdx.y * 4 + wv;           // 50*4 = 200 classes exactly

    const float* wr = gw + (size_t)c * Dsz + lane * 12;
    const float* cr = ct + (size_t)b * Dsz + lane * 12;
    float s = 0.f;
#pragma unroll
    for (int j = 0; j < 3; ++j) {
        const float4 w = *(const float4*)(wr + 4 * j);
        const float4 x = *(const float4*)(cr + 4 * j);
        s += w.x * x.x + w.y * x.y + w.z * x.z + w.w * x.w;
    }
#pragma unroll
    for (int off = 32; off > 0; off >>= 1) s += __shfl_down(s, off, 64);
    if (lane == 0) {
        const int o = b * Csz + c;
        out[o] = s + gb[c] + lam[0] * out[o] * (1.f / ((float)Ssz * (float)Dsz));
    }
}

extern "C" void kernel_launch(void* const* d_in, const int* in_sizes, int n_in,
                              void* d_out, int out_size, void* d_ws, size_t ws_size,
                              hipStream_t stream) {
    const float* X   = (const float*)d_in[0];
    const float* ct  = (const float*)d_in[1];
    const float* aw  = (const float*)d_in[2];
    const float* ab  = (const float*)d_in[3];
    const float* gw  = (const float*)d_in[4];
    const float* gb  = (const float*)d_in[5];
    const float* lam = (const float*)d_in[6];
    float* out = (float*)d_out;
    unsigned short* Wb = (unsigned short*)d_ws;     // 208*768*2 = 320 KB scratch

    hipMemsetAsync(out, 0, Bsz * Csz * sizeof(float), stream);
    prep_w<<<(NPAD * Dsz / 4) / 256, 256, 0, stream>>>(aw, Wb);
    attn_kernel<<<(Bsz * Ssz) / MT, 256, 0, stream>>>(X, Wb, ab, out);
    gc_kernel<<<dim3(Bsz, Csz / 4 / 1), 256, 0, stream>>>(ct, gw, gb, lam, out);
}

// Round 3
// 212.927 us; speedup vs baseline: 1.3890x; 1.2287x over previous
//
#include <hip/hip_runtime.h>
#include <math.h>

// (B,S,D,C) = (64, 576, 768, 200)
#define Bsz  64
#define Ssz  576
#define Dsz  768
#define Csz  200
#define NPAD 208        // 13 tiles of 16: cols 0..199 classes, col 200 = ones (rowsum), 201..207 zero
#define MT   64         // rows per block
#define BK   64         // K-tile
#define NKT  (Dsz / BK) // 12

typedef short short8 __attribute__((ext_vector_type(8)));
typedef float f32x4  __attribute__((ext_vector_type(4)));

#define AS_GLOBAL __attribute__((address_space(1)))
#define AS_LDS    __attribute__((address_space(3)))

__device__ inline unsigned short f2bf_rne(float f) {
    union { float f; unsigned int u; } v; v.f = f;
    return (unsigned short)((v.u + 0x7FFFu + ((v.u >> 16) & 1u)) >> 16);
}
// two fp32 -> packed bf16x2 (round-half-up): low16 = lo, high16 = hi
__device__ inline unsigned int pack2bf(float lo, float hi) {
    union { float f; unsigned int u; } a, b; a.f = lo; b.f = hi;
    return __builtin_amdgcn_perm(b.u + 0x8000u, a.u + 0x8000u, 0x07060302u);
}
// async 16B-per-lane global -> LDS (dest = wave-uniform base + lane*16)
__device__ inline void gload_lds16(const unsigned short* g, unsigned short* l) {
    __builtin_amdgcn_global_load_lds((const AS_GLOBAL unsigned int*)g,
                                     (AS_LDS unsigned int*)l, 16, 0, 0);
}

// one-time: W (200x768 fp32) -> bf16 (208x768); row 200 = 1.0 (rowsum trick), 201..207 = 0
__global__ __launch_bounds__(256) void prep_w(const float* __restrict__ W,
                                              unsigned short* __restrict__ Wb) {
    const int i   = blockIdx.x * 256 + threadIdx.x;   // float4-group index, NPAD*768/4 total
    const int row = i / (Dsz / 4);
    const int col = (i % (Dsz / 4)) * 4;
    ushort4 h;
    if (row < Csz) {
        const float4 v = *(const float4*)(W + (size_t)row * Dsz + col);
        h.x = f2bf_rne(v.x); h.y = f2bf_rne(v.y); h.z = f2bf_rne(v.z); h.w = f2bf_rne(v.w);
    } else if (row == Csz) {
        h.x = h.y = h.z = h.w = 0x3F80;               // bf16 1.0
    } else {
        h.x = h.y = h.z = h.w = 0;
    }
    *(ushort4*)(Wb + (size_t)row * Dsz + col) = h;
}

// Fused logits -> sigmoid -> rowsum-weighted reduction.
// X direct-to-fragment (no LDS, no barrier); W async dbuf in LDS, 1 barrier/iter.
__global__ __launch_bounds__(256, 3) void attn_kernel(
    const float* __restrict__ X,            // (B*S, D) fp32
    const unsigned short* __restrict__ Wb,  // (NPAD, D) bf16
    const float* __restrict__ attn_b,       // (C,)
    float* __restrict__ accum)              // (B, C) fp32, pre-zeroed (= d_out)
{
    // W tile: 208 rows x 64 bf16 = 128 B/row, XOR-swizzled chunks, double-buffered
    __shared__ unsigned short sW[2][NPAD * BK];       // 2 x 26624 B
    __shared__ float colsumL[NPAD];

    const int tid  = threadIdx.x;
    const int lane = tid & 63;
    const int wv   = tid >> 6;
    const int m    = lane & 15;     // A row within wave tile / B row within class tile
    const int q    = lane >> 4;     // k-quad
    const int rowbase = blockIdx.x * MT;
    const int bidx    = rowbase / Ssz;

    if (tid < NPAD) colsumL[tid] = 0.f;

    // ---- W staging assignment: 1664 16B-chunks = 26 wave-instrs, split 7/7/6/6
    const int wn   = (wv < 2) ? 7 : 6;                       // instrs for this wave
    const int grp0 = (wv < 2) ? wv * 7 : 14 + (wv - 2) * 6;  // first 64-slot group
    // lane's slot s = (grp0+j)*64 + lane; row = s>>3, cpos = s&7, global chunk = cpos ^ (row&7)
    const int s0    = grp0 * 64 + lane;
    const int wrow0 = s0 >> 3;
    const int wcg   = (s0 & 7) ^ (wrow0 & 7);   // invariant under row += 8
    const unsigned short* wg0 = Wb + (size_t)wrow0 * Dsz + wcg * 8;

    f32x4 acc[13];
#pragma unroll
    for (int t = 0; t < 13; ++t) acc[t] = (f32x4){0.f, 0.f, 0.f, 0.f};

    // ---- X direct-fragment base: lane owns row (wv*16+m), k-chunk q*8
    const float* xp = X + (size_t)(rowbase + wv * 16 + m) * Dsz + q * 8;

    // LDS read position for B-frags: byte addr = row_local*128 + cpos*16, cpos = (k2*4+q)^(m&7)
    const int cp0 = (q ^ (m & 7)) * 8;          // k2=0, in shorts
    const int cp1 = ((4 | q) ^ (m & 7)) * 8;    // k2=1

    // ---- prologue: issue W tile 0, load X tile 0
#pragma unroll
    for (int j = 0; j < 7; ++j)
        if (j < wn) gload_lds16(wg0 + (size_t)8 * j * Dsz, &sW[0][(grp0 + j) * 512]);
    float4 xr0 = *(const float4*)(xp);
    float4 xr1 = *(const float4*)(xp + 4);
    float4 xr2 = *(const float4*)(xp + 32);
    float4 xr3 = *(const float4*)(xp + 36);

#pragma unroll
    for (int kt = 0; kt < NKT; ++kt) {
        const int p = kt & 1;
        // barrier: sW[p^1] free for restage; vmcnt(0) drain => sW[p] (issued last iter) ready
        __syncthreads();
        if (kt + 1 < NKT) {
#pragma unroll
            for (int j = 0; j < 7; ++j)
                if (j < wn) gload_lds16(wg0 + (size_t)((kt + 1) * BK + 8 * j * Dsz),
                                        &sW[p ^ 1][(grp0 + j) * 512]);
        }
        // prefetch next X tile into regs (in flight across this iter's MFMA)
        float4 xn0, xn1, xn2, xn3;
        if (kt + 1 < NKT) {
            const float* xq = xp + (kt + 1) * BK;
            xn0 = *(const float4*)(xq);
            xn1 = *(const float4*)(xq + 4);
            xn2 = *(const float4*)(xq + 32);
            xn3 = *(const float4*)(xq + 36);
        }
        // ---- consume: A from regs, B from sW[p]
        union { short8 s; unsigned int u[4]; } a0, a1;
        a0.u[0] = pack2bf(xr0.x, xr0.y); a0.u[1] = pack2bf(xr0.z, xr0.w);
        a0.u[2] = pack2bf(xr1.x, xr1.y); a0.u[3] = pack2bf(xr1.z, xr1.w);
        a1.u[0] = pack2bf(xr2.x, xr2.y); a1.u[1] = pack2bf(xr2.z, xr2.w);
        a1.u[2] = pack2bf(xr3.x, xr3.y); a1.u[3] = pack2bf(xr3.z, xr3.w);
        const unsigned short* wp0 = &sW[p][m * 64 + cp0];
        const unsigned short* wp1 = &sW[p][m * 64 + cp1];
#pragma unroll
        for (int t = 0; t < 13; ++t) {
            const short8 b0 = *(const short8*)(wp0 + t * 1024);
            acc[t] = __builtin_amdgcn_mfma_f32_16x16x32_bf16(a0.s, b0, acc[t], 0, 0, 0);
        }
#pragma unroll
        for (int t = 0; t < 13; ++t) {
            const short8 b1 = *(const short8*)(wp1 + t * 1024);
            acc[t] = __builtin_amdgcn_mfma_f32_16x16x32_bf16(a1.s, b1, acc[t], 0, 0, 0);
        }
        xr0 = xn0; xr1 = xn1; xr2 = xn2; xr3 = xn3;
    }

    // ---- rowsum via ones-column: col 200 lives in tile 12, lanes with m==8.
    // Row (q*4+r) of this wave's slice is in lane q*16+8, reg r. Broadcast intra-wave.
    float rsv[4];
#pragma unroll
    for (int r = 0; r < 4; ++r) rsv[r] = __shfl(acc[12][r], (lane & 48) + 8, 64);

    // ---- epilogue: att = sigmoid(logit + bias); colsum[c] += att * rowsum[row]
    // C/D layout: col = lane&15, row = (lane>>4)*4 + reg
#pragma unroll
    for (int t = 0; t < 13; ++t) {
        const int c = t * 16 + m;
        if (c < Csz) {
            const float bias = attn_b[c];
            float s = 0.f;
#pragma unroll
            for (int r = 0; r < 4; ++r) {
                const float x = acc[t][r] + bias;
                s += rsv[r] / (1.f + __expf(-x));
            }
            atomicAdd(&colsumL[c], s);
        }
    }
    __syncthreads();
    if (tid < Csz) atomicAdd(&accum[bidx * Csz + tid], colsumL[tid]);
}

// global classifier + combine: wave-per-class, grid (B, 50)
__global__ __launch_bounds__(256) void gc_kernel(
    const float* __restrict__ ct,   // (B, D)
    const float* __restrict__ gw,   // (C, D)
    const float* __restrict__ gb,   // (C,)
    const float* __restrict__ lam,  // (1,)
    float* __restrict__ out)        // (B, C): attention accum on entry
{
    const int b    = blockIdx.x;
    const int wv   = threadIdx.x >> 6;
    const int lane = threadIdx.x & 63;
    const int c    = blockIdx.y * 4 + wv;

    const float* wr = gw + (size_t)c * Dsz + lane * 12;
    const float* cr = ct + (size_t)b * Dsz + lane * 12;
    float s = 0.f;
#pragma unroll
    for (int j = 0; j < 3; ++j) {
        const float4 w = *(const float4*)(wr + 4 * j);
        const float4 x = *(const float4*)(cr + 4 * j);
        s += w.x * x.x + w.y * x.y + w.z * x.z + w.w * x.w;
    }
#pragma unroll
    for (int off = 32; off > 0; off >>= 1) s += __shfl_down(s, off, 64);
    if (lane == 0) {
        const int o = b * Csz + c;
        out[o] = s + gb[c] + lam[0] * out[o] * (1.f / ((float)Ssz * (float)Dsz));
    }
}

extern "C" void kernel_launch(void* const* d_in, const int* in_sizes, int n_in,
                              void* d_out, int out_size, void* d_ws, size_t ws_size,
                              hipStream_t stream) {
    const float* X   = (const float*)d_in[0];
    const float* ct  = (const float*)d_in[1];
    const float* aw  = (const float*)d_in[2];
    const float* ab  = (const float*)d_in[3];
    const float* gw  = (const float*)d_in[4];
    const float* gb  = (const float*)d_in[5];
    const float* lam = (const float*)d_in[6];
    float* out = (float*)d_out;
    unsigned short* Wb = (unsigned short*)d_ws;     // 208*768*2 = 320 KB scratch

    hipMemsetAsync(out, 0, Bsz * Csz * sizeof(float), stream);
    prep_w<<<(NPAD * Dsz / 4) / 256, 256, 0, stream>>>(aw, Wb);
    attn_kernel<<<(Bsz * Ssz) / MT, 256, 0, stream>>>(X, Wb, ab, out);
    gc_kernel<<<dim3(Bsz, Csz / 4), 256, 0, stream>>>(ct, gw, gb, lam, out);
}